// Round 1
// 834.683 us; speedup vs baseline: 1.3983x; 1.3983x over previous
//
#include <hip/hip_runtime.h>
#include <stdint.h>

// LSTM cell. B=8192, IN=2048, H=2048.
// R3: 256x256 8-phase GEMM template (T1 XCD swizzle + T2 LDS XOR-swizzle +
// T3/T4 counted vmcnt + T5 setprio), wave grid 4M x 2N so the LSTM epilogue
// is fully in-register (no gate LDS buffer -> no ds_write bank conflicts).

#define BQ 8192
#define INF 2048
#define HH 2048
#define KK 4096   // IN + H

typedef __attribute__((ext_vector_type(8))) short short8;
typedef __attribute__((ext_vector_type(8))) unsigned short ushort8;
typedef __attribute__((ext_vector_type(4))) float floatx4;

__device__ __forceinline__ unsigned short f2b(float f) {
    unsigned u = __float_as_uint(f);
    u += 0x7fff + ((u >> 16) & 1);   // round-to-nearest-even
    return (unsigned short)(u >> 16);
}
__device__ __forceinline__ ushort8 cvt8(float4 a, float4 b) {
    ushort8 y;
    y[0] = f2b(a.x); y[1] = f2b(a.y); y[2] = f2b(a.z); y[3] = f2b(a.w);
    y[4] = f2b(b.x); y[5] = f2b(b.y); y[6] = f2b(b.z); y[7] = f2b(b.w);
    return y;
}

// ---- pack [input | h_prev] -> bf16 combined [8192][4096] ----
__global__ __launch_bounds__(256) void pack_combined(
    const float4* __restrict__ inp, const float4* __restrict__ hp,
    unsigned short* __restrict__ dst)
{
    const int PER8 = BQ * INF / 8;
    int v = blockIdx.x * 256 + threadIdx.x;
    int isH = v >= PER8;
    int u8 = (isH ? (v - PER8) : v);
    const float4* src = isH ? hp : inp;
    float4 x0 = src[u8 * 2];
    float4 x1 = src[u8 * 2 + 1];
    int u = u8 * 8;
    int b = u >> 11;
    int k = u & 2047;
    size_t off = (size_t)b * KK + k + (isH ? INF : 0);
    *(ushort8*)(dst + off) = cvt8(x0, x1);
}

// ---- pack Wf..Wo -> bf16 W [8192][4096], gate-interleaved rows ----
// packed row p = (h>>5)*128 + gate*32 + (h&31)
__global__ __launch_bounds__(256) void pack_w(
    const float4* __restrict__ w0, const float4* __restrict__ w1,
    const float4* __restrict__ w2, const float4* __restrict__ w3,
    unsigned short* __restrict__ dst)
{
    int v = blockIdx.x * 256 + threadIdx.x;
    size_t e = (size_t)v * 8;
    int g = (int)(e >> 23);
    int u = (int)(e & ((1u << 23) - 1));
    int h = u >> 12;
    int k = u & 4095;
    const float4* src = (g == 0) ? w0 : (g == 1) ? w1 : (g == 2) ? w2 : w3;
    float4 x0 = src[u >> 2];
    float4 x1 = src[(u >> 2) + 1];
    int p = ((h >> 5) << 7) + (g << 5) + (h & 31);
    *(ushort8*)(dst + (size_t)p * KK + k) = cvt8(x0, x1);
}

// ---- fused 256x256 8-phase GEMM + in-register LSTM epilogue ----
// 512 threads = 8 waves, wave grid 4(M) x 2(N): per-wave 64 rows x 128 cols.
// LDS 128 KiB: [A0 | B0 | A1 | B1] @ 32 KiB each, each = 2 halves of
// [128 rows][64 k] bf16 (128 B rows), XOR-swizzled byte^=((row&7)<<4).
// Staging: global_load_lds (linear dest) with pre-swizzled global source.
__global__ __launch_bounds__(512, 2) void lstm_fused(
    const unsigned short* __restrict__ A,   // combined bf16 [8192][4096]
    const unsigned short* __restrict__ W,   // packed bf16 [8192][4096]
    const float* __restrict__ cprev,
    const float* __restrict__ bf_, const float* __restrict__ bi_,
    const float* __restrict__ bg_, const float* __restrict__ bo_,
    float* __restrict__ out)
{
    __shared__ unsigned short lds[65536];   // 128 KiB
    char* ldsb = (char*)lds;

    const int t    = threadIdx.x;
    const int wv   = t >> 6;
    const int lane = t & 63;
    const int wm   = wv >> 1;      // 0..3 -> row base wm*64
    const int wn   = wv & 1;       // 0..1 -> col base wn*128
    const int fr   = lane & 15;
    const int fq   = lane >> 4;

    // bijective XCD swizzle (1024 wgs, 1024%8==0)
    int lin = blockIdx.y * 32 + blockIdx.x;
    lin = (lin & 7) * 128 + (lin >> 3);
    const int m0 = (lin >> 5) << 8;        // batch tile base (256 rows)
    const int n0 = (lin & 31) << 8;        // packed-col tile base (256)

    // staging source: lane covers row (wv*16 + lane>>3), swizzled k-chunk
    const int koff = ((lane & 7) ^ (lane >> 3)) << 3;   // elements
    const unsigned short* aR = A + (size_t)(m0 + wv * 16 + (lane >> 3)) * KK + koff;
    const unsigned short* bR = W + (size_t)(n0 + wv * 16 + (lane >> 3)) * KK + koff;
    const int stgOff = wv * 16 * 128;      // LDS byte offset of wave's 16 rows

    // fragment-read bases (byte offsets into LDS)
    const int x7    = fr & 7;
    const int aBase = (wm >> 1) * 16384 + ((wm & 1) * 64 + fr) * 128;
    const int bBase = 32768 + wn * 16384 + fr * 128;

    floatx4 acc[4][8];
#pragma unroll
    for (int i = 0; i < 4; ++i)
#pragma unroll
        for (int j = 0; j < 8; ++j) acc[i][j] = (floatx4)0.f;

    short8 aA[2][2];   // two A fragments (i, i+1) x ks
    short8 bb[8][2];   // all 8 B fragments x ks

#define STAGE(srcbase, ldsoff, kk)                                              \
    do {                                                                        \
        __builtin_amdgcn_global_load_lds(                                       \
            (const __attribute__((address_space(1))) void*)((srcbase) + (kk)),  \
            (__attribute__((address_space(3))) void*)(ldsb + (ldsoff) + stgOff),\
            16, 0, 0);                                                          \
        __builtin_amdgcn_global_load_lds(                                       \
            (const __attribute__((address_space(1))) void*)((srcbase) + 8 * KK + (kk)), \
            (__attribute__((address_space(3))) void*)(ldsb + (ldsoff) + stgOff + 1024), \
            16, 0, 0);                                                          \
    } while (0)

    auto LDA = [&](int side, int i, short8* d) {
        const char* p = ldsb + side * 65536 + aBase + i * 2048;
        d[0] = *(const short8*)(p + ((fq ^ x7) << 4));
        d[1] = *(const short8*)(p + (((4 + fq) ^ x7) << 4));
    };
    auto LDB = [&](int side, int j, short8* d) {
        const char* p = ldsb + side * 65536 + bBase + j * 2048;
        d[0] = *(const short8*)(p + ((fq ^ x7) << 4));
        d[1] = *(const short8*)(p + (((4 + fq) ^ x7) << 4));
    };
    auto MM = [&](const short8* a, const short8* b, floatx4& c) {
        c = __builtin_amdgcn_mfma_f32_16x16x32_bf16(a[0], b[0], c, 0, 0, 0);
        c = __builtin_amdgcn_mfma_f32_16x16x32_bf16(a[1], b[1], c, 0, 0, 0);
    };

#define BAR()  __builtin_amdgcn_s_barrier()
#define SB0()  __builtin_amdgcn_sched_barrier(0)
#define WLGKM() do { asm volatile("s_waitcnt lgkmcnt(0)" ::: "memory"); SB0(); } while (0)
#define VM4()  do { asm volatile("s_waitcnt vmcnt(4)" ::: "memory"); SB0(); } while (0)

    // prologue: tile0 -> side0 (A lo/hi, B lo/hi), tile1 B -> side1
    STAGE(aR, 0, 0);
    STAGE(aR + 128 * KK, 16384, 0);
    STAGE(bR, 32768, 0);
    STAGE(bR + 128 * KK, 49152, 0);
    STAGE(bR, 98304, 64);
    STAGE(bR + 128 * KK, 114688, 64);
    VM4();   // tile0 fully landed, tile1-B may be in flight
    BAR();

#pragma unroll 1
    for (int it = 0; it < 32; ++it) {
        const int k1 = ((2 * it + 1) & 63) << 6;
        const int k2 = ((2 * it + 2) & 63) << 6;
        const int k3 = ((2 * it + 3) & 63) << 6;

        // ---- ph1: side0 reads a0,a1,b0-3; stage A-lo(u+1)->side1 ----
        LDA(0, 0, aA[0]); LDA(0, 1, aA[1]);
        LDB(0, 0, bb[0]); LDB(0, 1, bb[1]); LDB(0, 2, bb[2]); LDB(0, 3, bb[3]);
        STAGE(aR, 65536, k1);
        SB0(); BAR(); WLGKM();
        __builtin_amdgcn_s_setprio(1);
#pragma unroll
        for (int ia = 0; ia < 2; ++ia)
#pragma unroll
            for (int j = 0; j < 4; ++j) MM(aA[ia], bb[j], acc[ia][j]);
        __builtin_amdgcn_s_setprio(0);
        BAR();

        // ---- ph2: b4-7; stage A-hi(u+1)->side1 ----
        LDB(0, 4, bb[4]); LDB(0, 5, bb[5]); LDB(0, 6, bb[6]); LDB(0, 7, bb[7]);
        STAGE(aR + 128 * KK, 81920, k1);
        SB0(); BAR(); WLGKM();
        __builtin_amdgcn_s_setprio(1);
#pragma unroll
        for (int ia = 0; ia < 2; ++ia)
#pragma unroll
            for (int j = 0; j < 4; ++j) MM(aA[ia], bb[4 + j], acc[ia][4 + j]);
        __builtin_amdgcn_s_setprio(0);
        BAR();

        // ---- ph3: a2,a3; stage B-lo(u+2)->side0 (B side0 dead after ph2) ----
        LDA(0, 2, aA[0]); LDA(0, 3, aA[1]);
        STAGE(bR, 32768, k2);
        SB0(); BAR(); WLGKM();
        __builtin_amdgcn_s_setprio(1);
#pragma unroll
        for (int ia = 0; ia < 2; ++ia)
#pragma unroll
            for (int j = 0; j < 4; ++j) MM(aA[ia], bb[4 + j], acc[2 + ia][4 + j]);
        __builtin_amdgcn_s_setprio(0);
        BAR();

        // ---- ph4: no reads; stage B-hi(u+2); counted vmcnt ----
        STAGE(bR + 128 * KK, 49152, k2);
        SB0(); BAR();
        __builtin_amdgcn_s_setprio(1);
#pragma unroll
        for (int ia = 0; ia < 2; ++ia)
#pragma unroll
            for (int j = 0; j < 4; ++j) MM(aA[ia], bb[j], acc[2 + ia][j]);
        __builtin_amdgcn_s_setprio(0);
        VM4();   // A(u+1)+B(u+1) landed for ph5; keep B(u+2) in flight
        BAR();

        // ---- ph5: side1 reads a0,a1,b0-3; stage A-lo(u+2)->side0 ----
        LDA(1, 0, aA[0]); LDA(1, 1, aA[1]);
        LDB(1, 0, bb[0]); LDB(1, 1, bb[1]); LDB(1, 2, bb[2]); LDB(1, 3, bb[3]);
        STAGE(aR, 0, k2);
        SB0(); BAR(); WLGKM();
        __builtin_amdgcn_s_setprio(1);
#pragma unroll
        for (int ia = 0; ia < 2; ++ia)
#pragma unroll
            for (int j = 0; j < 4; ++j) MM(aA[ia], bb[j], acc[ia][j]);
        __builtin_amdgcn_s_setprio(0);
        BAR();

        // ---- ph6: b4-7; stage A-hi(u+2)->side0 ----
        LDB(1, 4, bb[4]); LDB(1, 5, bb[5]); LDB(1, 6, bb[6]); LDB(1, 7, bb[7]);
        STAGE(aR + 128 * KK, 16384, k2);
        SB0(); BAR(); WLGKM();
        __builtin_amdgcn_s_setprio(1);
#pragma unroll
        for (int ia = 0; ia < 2; ++ia)
#pragma unroll
            for (int j = 0; j < 4; ++j) MM(aA[ia], bb[4 + j], acc[ia][4 + j]);
        __builtin_amdgcn_s_setprio(0);
        BAR();

        // ---- ph7: a2,a3; stage B-lo(u+3)->side1 ----
        LDA(1, 2, aA[0]); LDA(1, 3, aA[1]);
        STAGE(bR, 98304, k3);
        SB0(); BAR(); WLGKM();
        __builtin_amdgcn_s_setprio(1);
#pragma unroll
        for (int ia = 0; ia < 2; ++ia)
#pragma unroll
            for (int j = 0; j < 4; ++j) MM(aA[ia], bb[4 + j], acc[2 + ia][4 + j]);
        __builtin_amdgcn_s_setprio(0);
        BAR();

        // ---- ph8: no reads; stage B-hi(u+3); counted vmcnt ----
        STAGE(bR + 128 * KK, 114688, k3);
        SB0(); BAR();
        __builtin_amdgcn_s_setprio(1);
#pragma unroll
        for (int ia = 0; ia < 2; ++ia)
#pragma unroll
            for (int j = 0; j < 4; ++j) MM(aA[ia], bb[j], acc[2 + ia][j]);
        __builtin_amdgcn_s_setprio(0);
        VM4();   // tile(u+2) landed for next ph1; keep B(u+3) in flight
        BAR();
    }

    // ---- in-register LSTM epilogue ----
    // acc[i][j][r]: row = m0 + wm*64 + i*16 + fq*4 + r
    //              packed col = n0 + wn*128 + j*16 + fr
    //              -> gate = j>>1, h = (n0>>2) + wn*32 + (j&1)*16 + fr
    const int hb = (n0 >> 2) + wn * 32;
    float bF[2], bI[2], bG[2], bO[2];
#pragma unroll
    for (int jh = 0; jh < 2; ++jh) {
        int h = hb + jh * 16 + fr;
        bF[jh] = bf_[h]; bI[jh] = bi_[h]; bG[jh] = bg_[h]; bO[jh] = bo_[h];
    }
    const int rowb = m0 + wm * 64 + fq * 4;
#pragma unroll
    for (int i = 0; i < 4; ++i) {
#pragma unroll
        for (int r = 0; r < 4; ++r) {
            int row = rowb + i * 16 + r;
#pragma unroll
            for (int jh = 0; jh < 2; ++jh) {
                int h = hb + jh * 16 + fr;
                size_t gi = (size_t)row * HH + h;
                float xf = acc[i][0 + jh][r] + bF[jh];
                float xi = acc[i][2 + jh][r] + bI[jh];
                float xg = acc[i][4 + jh][r] + bG[jh];
                float xo = acc[i][6 + jh][r] + bO[jh];
                float f  = 1.f / (1.f + __expf(-xf));
                float ii = 1.f / (1.f + __expf(-xi));
                float g  = tanhf(xg);
                float o  = 1.f / (1.f + __expf(-xo));
                float c  = f * cprev[gi] + ii * g;
                float hv = o * tanhf(c);
                out[gi] = hv;
                out[(size_t)BQ * HH + gi] = c;
            }
        }
    }
}

extern "C" void kernel_launch(void* const* d_in, const int* in_sizes, int n_in,
                              void* d_out, int out_size, void* d_ws, size_t ws_size,
                              hipStream_t stream) {
    const float* input  = (const float*)d_in[0];
    const float* h_prev = (const float*)d_in[1];
    const float* c_prev = (const float*)d_in[2];
    const float* Wf = (const float*)d_in[3];
    const float* bf_ = (const float*)d_in[4];
    const float* Wi = (const float*)d_in[5];
    const float* bi_ = (const float*)d_in[6];
    const float* Wg = (const float*)d_in[7];
    const float* bg_ = (const float*)d_in[8];
    const float* Wo = (const float*)d_in[9];
    const float* bo_ = (const float*)d_in[10];
    float* out = (float*)d_out;

    unsigned short* combined = (unsigned short*)d_ws;                   // 64 MB
    unsigned short* Wpk = (unsigned short*)d_ws + (size_t)BQ * KK;      // 64 MB

    pack_combined<<<dim3(2 * BQ * INF / 8 / 256), 256, 0, stream>>>(
        (const float4*)input, (const float4*)h_prev, combined);
    pack_w<<<dim3(4 * HH * KK / 8 / 256), 256, 0, stream>>>(
        (const float4*)Wf, (const float4*)Wi, (const float4*)Wg, (const float4*)Wo, Wpk);
    lstm_fused<<<dim3(32, 32), 512, 0, stream>>>(
        combined, Wpk, c_prev, bf_, bi_, bg_, bo_, out);
}

// Round 2
// 818.203 us; speedup vs baseline: 1.4265x; 1.0201x over previous
//
#include <hip/hip_runtime.h>
#include <stdint.h>

// LSTM cell. B=8192, IN=2048, H=2048.
// R4: (a) remove forced lgkmcnt(0) drains from the 8-phase GEMM — let the
// compiler emit counted lgkmcnt per ds_read->MFMA dep (loads are compiler-
// visible; validity is guarded by counted vmcnt asm + barriers);
// (b) merge both pack kernels into one 16-elem/thread kernel (one launch);
// (c) fast tanh via __expf in the in-register epilogue.

#define BQ 8192
#define INF 2048
#define HH 2048
#define KK 4096   // IN + H

typedef __attribute__((ext_vector_type(8))) short short8;
typedef __attribute__((ext_vector_type(8))) unsigned short ushort8;
typedef __attribute__((ext_vector_type(4))) float floatx4;

__device__ __forceinline__ unsigned short f2b(float f) {
    unsigned u = __float_as_uint(f);
    u += 0x7fff + ((u >> 16) & 1);   // round-to-nearest-even
    return (unsigned short)(u >> 16);
}
__device__ __forceinline__ ushort8 cvt8(float4 a, float4 b) {
    ushort8 y;
    y[0] = f2b(a.x); y[1] = f2b(a.y); y[2] = f2b(a.z); y[3] = f2b(a.w);
    y[4] = f2b(b.x); y[5] = f2b(b.y); y[6] = f2b(b.z); y[7] = f2b(b.w);
    return y;
}
__device__ __forceinline__ float fsig(float x) {
    return 1.f / (1.f + __expf(-x));
}
__device__ __forceinline__ float ftanh(float x) {
    // saturates correctly: x>>0 -> 1-0 = 1 ; x<<0 -> 1-2 = -1
    return 1.f - 2.f / (__expf(2.f * x) + 1.f);
}

// ---- single pack kernel: [input|h_prev] -> combined bf16 [8192][4096],
//      Wf..Wo -> gate-interleaved bf16 W [8192][4096] (p=(h>>5)*128+g*32+(h&31))
//      16 elems / thread. 4,194,304 threads total.
__global__ __launch_bounds__(256) void pack_all(
    const float4* __restrict__ inp, const float4* __restrict__ hp,
    const float4* __restrict__ w0, const float4* __restrict__ w1,
    const float4* __restrict__ w2, const float4* __restrict__ w3,
    unsigned short* __restrict__ comb, unsigned short* __restrict__ wpk)
{
    const int NC16 = BQ * INF / 16;             // 1,048,576 per source
    int v = blockIdx.x * 256 + threadIdx.x;
    if (v < 2 * NC16) {
        int isH = v >= NC16;
        int u16 = v - (isH ? NC16 : 0);
        const float4* src = isH ? hp : inp;
        float4 x0 = src[u16 * 4];
        float4 x1 = src[u16 * 4 + 1];
        float4 x2 = src[u16 * 4 + 2];
        float4 x3 = src[u16 * 4 + 3];
        int u = u16 * 16;
        int b = u >> 11;                        // 2048 elems per source row
        int k = u & 2047;
        unsigned short* d = comb + (size_t)b * KK + k + (isH ? INF : 0);
        *(ushort8*)d       = cvt8(x0, x1);
        *(ushort8*)(d + 8) = cvt8(x2, x3);
    } else {
        int w = v - 2 * NC16;                   // 0..2,097,151
        size_t e = (size_t)w * 16;
        int g = (int)(e >> 23);                 // 2^23 elems per gate
        int u = (int)(e & ((1u << 23) - 1));
        int h = u >> 12;                        // 4096 per row
        int k = u & 4095;
        const float4* src = (g == 0) ? w0 : (g == 1) ? w1 : (g == 2) ? w2 : w3;
        float4 x0 = src[(u >> 2)];
        float4 x1 = src[(u >> 2) + 1];
        float4 x2 = src[(u >> 2) + 2];
        float4 x3 = src[(u >> 2) + 3];
        int p = ((h >> 5) << 7) + (g << 5) + (h & 31);
        unsigned short* d = wpk + (size_t)p * KK + k;
        *(ushort8*)d       = cvt8(x0, x1);
        *(ushort8*)(d + 8) = cvt8(x2, x3);
    }
}

// ---- fused 256x256 8-phase GEMM + in-register LSTM epilogue ----
// 512 threads = 8 waves, wave grid 4(M) x 2(N): per-wave 64 rows x 128 cols.
// LDS 128 KiB: [A0 | B0 | A1 | B1] @ 32 KiB each, XOR-swizzled 16B chunks.
// Staging: global_load_lds (linear dest) with pre-swizzled global source.
// Sync: counted vmcnt(4) at ph4/ph8 only; NO forced lgkm drain — compiler
// emits counted lgkmcnt per ds_read->MFMA dependency.
__global__ __launch_bounds__(512, 2) void lstm_fused(
    const unsigned short* __restrict__ A,   // combined bf16 [8192][4096]
    const unsigned short* __restrict__ W,   // packed bf16 [8192][4096]
    const float* __restrict__ cprev,
    const float* __restrict__ bf_, const float* __restrict__ bi_,
    const float* __restrict__ bg_, const float* __restrict__ bo_,
    float* __restrict__ out)
{
    __shared__ unsigned short lds[65536];   // 128 KiB
    char* ldsb = (char*)lds;

    const int t    = threadIdx.x;
    const int wv   = t >> 6;
    const int lane = t & 63;
    const int wm   = wv >> 1;      // 0..3 -> row base wm*64
    const int wn   = wv & 1;       // 0..1 -> col base wn*128
    const int fr   = lane & 15;
    const int fq   = lane >> 4;

    // bijective XCD swizzle (1024 wgs, 1024%8==0)
    int lin = blockIdx.y * 32 + blockIdx.x;
    lin = (lin & 7) * 128 + (lin >> 3);
    const int m0 = (lin >> 5) << 8;        // batch tile base (256 rows)
    const int n0 = (lin & 31) << 8;        // packed-col tile base (256)

    // staging source: lane covers row (wv*16 + lane>>3), swizzled k-chunk
    const int koff = ((lane & 7) ^ (lane >> 3)) << 3;   // elements
    const unsigned short* aR = A + (size_t)(m0 + wv * 16 + (lane >> 3)) * KK + koff;
    const unsigned short* bR = W + (size_t)(n0 + wv * 16 + (lane >> 3)) * KK + koff;
    const int stgOff = wv * 16 * 128;      // LDS byte offset of wave's 16 rows

    // fragment-read bases (byte offsets into LDS)
    const int x7    = fr & 7;
    const int aBase = (wm >> 1) * 16384 + ((wm & 1) * 64 + fr) * 128;
    const int bBase = 32768 + wn * 16384 + fr * 128;

    floatx4 acc[4][8];
#pragma unroll
    for (int i = 0; i < 4; ++i)
#pragma unroll
        for (int j = 0; j < 8; ++j) acc[i][j] = (floatx4)0.f;

    short8 aA[2][2];   // two A fragments (i, i+1) x ks
    short8 bb[8][2];   // all 8 B fragments x ks

#define STAGE(srcbase, ldsoff, kk)                                              \
    do {                                                                        \
        __builtin_amdgcn_global_load_lds(                                       \
            (const __attribute__((address_space(1))) void*)((srcbase) + (kk)),  \
            (__attribute__((address_space(3))) void*)(ldsb + (ldsoff) + stgOff),\
            16, 0, 0);                                                          \
        __builtin_amdgcn_global_load_lds(                                       \
            (const __attribute__((address_space(1))) void*)((srcbase) + 8 * KK + (kk)), \
            (__attribute__((address_space(3))) void*)(ldsb + (ldsoff) + stgOff + 1024), \
            16, 0, 0);                                                          \
    } while (0)

    auto LDA = [&](int side, int i, short8* d) {
        const char* p = ldsb + side * 65536 + aBase + i * 2048;
        d[0] = *(const short8*)(p + ((fq ^ x7) << 4));
        d[1] = *(const short8*)(p + (((4 + fq) ^ x7) << 4));
    };
    auto LDB = [&](int side, int j, short8* d) {
        const char* p = ldsb + side * 65536 + bBase + j * 2048;
        d[0] = *(const short8*)(p + ((fq ^ x7) << 4));
        d[1] = *(const short8*)(p + (((4 + fq) ^ x7) << 4));
    };
    auto MM = [&](const short8* a, const short8* b, floatx4& c) {
        c = __builtin_amdgcn_mfma_f32_16x16x32_bf16(a[0], b[0], c, 0, 0, 0);
        c = __builtin_amdgcn_mfma_f32_16x16x32_bf16(a[1], b[1], c, 0, 0, 0);
    };

#define BAR()  __builtin_amdgcn_s_barrier()
#define SB0()  __builtin_amdgcn_sched_barrier(0)
#define VM4()  do { asm volatile("s_waitcnt vmcnt(4)" ::: "memory"); SB0(); } while (0)

    // prologue: tile0 -> side0 (A lo/hi, B lo/hi), tile1 B -> side1
    STAGE(aR, 0, 0);
    STAGE(aR + 128 * KK, 16384, 0);
    STAGE(bR, 32768, 0);
    STAGE(bR + 128 * KK, 49152, 0);
    STAGE(bR, 98304, 64);
    STAGE(bR + 128 * KK, 114688, 64);
    VM4();   // tile0 fully landed, tile1-B may be in flight
    BAR();

#pragma unroll 1
    for (int it = 0; it < 32; ++it) {
        const int k1 = ((2 * it + 1) & 63) << 6;
        const int k2 = ((2 * it + 2) & 63) << 6;
        const int k3 = ((2 * it + 3) & 63) << 6;

        // ---- ph1: side0 reads a0,a1,b0-3; stage A-lo(u+1)->side1 ----
        LDA(0, 0, aA[0]); LDA(0, 1, aA[1]);
        LDB(0, 0, bb[0]); LDB(0, 1, bb[1]); LDB(0, 2, bb[2]); LDB(0, 3, bb[3]);
        STAGE(aR, 65536, k1);
        SB0(); BAR();
        __builtin_amdgcn_s_setprio(1);
#pragma unroll
        for (int ia = 0; ia < 2; ++ia)
#pragma unroll
            for (int j = 0; j < 4; ++j) MM(aA[ia], bb[j], acc[ia][j]);
        __builtin_amdgcn_s_setprio(0);
        BAR();

        // ---- ph2: b4-7; stage A-hi(u+1)->side1 ----
        LDB(0, 4, bb[4]); LDB(0, 5, bb[5]); LDB(0, 6, bb[6]); LDB(0, 7, bb[7]);
        STAGE(aR + 128 * KK, 81920, k1);
        SB0(); BAR();
        __builtin_amdgcn_s_setprio(1);
#pragma unroll
        for (int ia = 0; ia < 2; ++ia)
#pragma unroll
            for (int j = 0; j < 4; ++j) MM(aA[ia], bb[4 + j], acc[ia][4 + j]);
        __builtin_amdgcn_s_setprio(0);
        BAR();

        // ---- ph3: a2,a3; stage B-lo(u+2)->side0 (B side0 dead after ph2) ----
        LDA(0, 2, aA[0]); LDA(0, 3, aA[1]);
        STAGE(bR, 32768, k2);
        SB0(); BAR();
        __builtin_amdgcn_s_setprio(1);
#pragma unroll
        for (int ia = 0; ia < 2; ++ia)
#pragma unroll
            for (int j = 0; j < 4; ++j) MM(aA[ia], bb[4 + j], acc[2 + ia][4 + j]);
        __builtin_amdgcn_s_setprio(0);
        BAR();

        // ---- ph4: no reads; stage B-hi(u+2); counted vmcnt ----
        STAGE(bR + 128 * KK, 49152, k2);
        SB0(); BAR();
        __builtin_amdgcn_s_setprio(1);
#pragma unroll
        for (int ia = 0; ia < 2; ++ia)
#pragma unroll
            for (int j = 0; j < 4; ++j) MM(aA[ia], bb[j], acc[2 + ia][j]);
        __builtin_amdgcn_s_setprio(0);
        VM4();   // A(u+1)+B(u+1) landed for ph5; keep B(u+2) in flight
        BAR();

        // ---- ph5: side1 reads a0,a1,b0-3; stage A-lo(u+2)->side0 ----
        LDA(1, 0, aA[0]); LDA(1, 1, aA[1]);
        LDB(1, 0, bb[0]); LDB(1, 1, bb[1]); LDB(1, 2, bb[2]); LDB(1, 3, bb[3]);
        STAGE(aR, 0, k2);
        SB0(); BAR();
        __builtin_amdgcn_s_setprio(1);
#pragma unroll
        for (int ia = 0; ia < 2; ++ia)
#pragma unroll
            for (int j = 0; j < 4; ++j) MM(aA[ia], bb[j], acc[ia][j]);
        __builtin_amdgcn_s_setprio(0);
        BAR();

        // ---- ph6: b4-7; stage A-hi(u+2)->side0 ----
        LDB(1, 4, bb[4]); LDB(1, 5, bb[5]); LDB(1, 6, bb[6]); LDB(1, 7, bb[7]);
        STAGE(aR + 128 * KK, 16384, k2);
        SB0(); BAR();
        __builtin_amdgcn_s_setprio(1);
#pragma unroll
        for (int ia = 0; ia < 2; ++ia)
#pragma unroll
            for (int j = 0; j < 4; ++j) MM(aA[ia], bb[4 + j], acc[ia][4 + j]);
        __builtin_amdgcn_s_setprio(0);
        BAR();

        // ---- ph7: a2,a3; stage B-lo(u+3)->side1 ----
        LDA(1, 2, aA[0]); LDA(1, 3, aA[1]);
        STAGE(bR, 98304, k3);
        SB0(); BAR();
        __builtin_amdgcn_s_setprio(1);
#pragma unroll
        for (int ia = 0; ia < 2; ++ia)
#pragma unroll
            for (int j = 0; j < 4; ++j) MM(aA[ia], bb[4 + j], acc[2 + ia][4 + j]);
        __builtin_amdgcn_s_setprio(0);
        BAR();

        // ---- ph8: no reads; stage B-hi(u+3); counted vmcnt ----
        STAGE(bR + 128 * KK, 114688, k3);
        SB0(); BAR();
        __builtin_amdgcn_s_setprio(1);
#pragma unroll
        for (int ia = 0; ia < 2; ++ia)
#pragma unroll
            for (int j = 0; j < 4; ++j) MM(aA[ia], bb[j], acc[2 + ia][j]);
        __builtin_amdgcn_s_setprio(0);
        VM4();   // tile(u+2) landed for next ph1; keep B(u+3) in flight
        BAR();
    }

    // ---- in-register LSTM epilogue ----
    // acc[i][j][r]: row = m0 + wm*64 + i*16 + fq*4 + r
    //              packed col = n0 + wn*128 + j*16 + fr
    //              -> gate = j>>1, h = (n0>>2) + wn*32 + (j&1)*16 + fr
    const int hb = (n0 >> 2) + wn * 32;
    float bF[2], bI[2], bG[2], bO[2];
#pragma unroll
    for (int jh = 0; jh < 2; ++jh) {
        int h = hb + jh * 16 + fr;
        bF[jh] = bf_[h]; bI[jh] = bi_[h]; bG[jh] = bg_[h]; bO[jh] = bo_[h];
    }
    const int rowb = m0 + wm * 64 + fq * 4;
#pragma unroll
    for (int i = 0; i < 4; ++i) {
#pragma unroll
        for (int r = 0; r < 4; ++r) {
            int row = rowb + i * 16 + r;
#pragma unroll
            for (int jh = 0; jh < 2; ++jh) {
                int h = hb + jh * 16 + fr;
                size_t gi = (size_t)row * HH + h;
                float xf = acc[i][0 + jh][r] + bF[jh];
                float xi = acc[i][2 + jh][r] + bI[jh];
                float xg = acc[i][4 + jh][r] + bG[jh];
                float xo = acc[i][6 + jh][r] + bO[jh];
                float f  = fsig(xf);
                float ii = fsig(xi);
                float g  = ftanh(xg);
                float o  = fsig(xo);
                float c  = f * cprev[gi] + ii * g;
                float hv = o * ftanh(c);
                out[gi] = hv;
                out[(size_t)BQ * HH + gi] = c;
            }
        }
    }
}

extern "C" void kernel_launch(void* const* d_in, const int* in_sizes, int n_in,
                              void* d_out, int out_size, void* d_ws, size_t ws_size,
                              hipStream_t stream) {
    const float* input  = (const float*)d_in[0];
    const float* h_prev = (const float*)d_in[1];
    const float* c_prev = (const float*)d_in[2];
    const float* Wf = (const float*)d_in[3];
    const float* bf_ = (const float*)d_in[4];
    const float* Wi = (const float*)d_in[5];
    const float* bi_ = (const float*)d_in[6];
    const float* Wg = (const float*)d_in[7];
    const float* bg_ = (const float*)d_in[8];
    const float* Wo = (const float*)d_in[9];
    const float* bo_ = (const float*)d_in[10];
    float* out = (float*)d_out;

    unsigned short* combined = (unsigned short*)d_ws;                   // 64 MB
    unsigned short* Wpk = (unsigned short*)d_ws + (size_t)BQ * KK;      // 64 MB

    pack_all<<<dim3(16384), 256, 0, stream>>>(
        (const float4*)input, (const float4*)h_prev,
        (const float4*)Wf, (const float4*)Wi, (const float4*)Wg, (const float4*)Wo,
        combined, Wpk);
    lstm_fused<<<dim3(32, 32), 512, 0, stream>>>(
        combined, Wpk, c_prev, bf_, bi_, bg_, bo_, out);
}

// Round 3
// 806.589 us; speedup vs baseline: 1.4470x; 1.0144x over previous
//
#include <hip/hip_runtime.h>
#include <stdint.h>

// LSTM cell. B=8192, IN=2048, H=2048.
// R5: rebalance 8-phase GEMM reads. Old quadrant order issued 12/8/4/0
// ds_read_b128 per phase (ph1 LDS-read-bound: 96 KB vs 621-cyc MFMA budget).
// New "all-A x B-pair" phases: 12/4/4/4. Staging re-slotted for new LDS
// liveness: B(u+1)->s1 @ph1/2, A(u+2)->s0 @ph3/4, B(u+2)->s0 @ph5/6,
// A(u+3)->s1 @ph7/8; vmcnt(4) at ph4/ph8 unchanged (FIFO accounting holds).

#define BQ 8192
#define INF 2048
#define HH 2048
#define KK 4096   // IN + H

typedef __attribute__((ext_vector_type(8))) short short8;
typedef __attribute__((ext_vector_type(8))) unsigned short ushort8;
typedef __attribute__((ext_vector_type(4))) float floatx4;

__device__ __forceinline__ unsigned short f2b(float f) {
    unsigned u = __float_as_uint(f);
    u += 0x7fff + ((u >> 16) & 1);   // round-to-nearest-even
    return (unsigned short)(u >> 16);
}
__device__ __forceinline__ ushort8 cvt8(float4 a, float4 b) {
    ushort8 y;
    y[0] = f2b(a.x); y[1] = f2b(a.y); y[2] = f2b(a.z); y[3] = f2b(a.w);
    y[4] = f2b(b.x); y[5] = f2b(b.y); y[6] = f2b(b.z); y[7] = f2b(b.w);
    return y;
}
__device__ __forceinline__ float fsig(float x) {
    return 1.f / (1.f + __expf(-x));
}
__device__ __forceinline__ float ftanh(float x) {
    return 1.f - 2.f / (__expf(2.f * x) + 1.f);
}

// ---- single pack kernel: [input|h_prev] -> combined bf16 [8192][4096],
//      Wf..Wo -> gate-interleaved bf16 W [8192][4096] (p=(h>>5)*128+g*32+(h&31))
__global__ __launch_bounds__(256) void pack_all(
    const float4* __restrict__ inp, const float4* __restrict__ hp,
    const float4* __restrict__ w0, const float4* __restrict__ w1,
    const float4* __restrict__ w2, const float4* __restrict__ w3,
    unsigned short* __restrict__ comb, unsigned short* __restrict__ wpk)
{
    const int NC16 = BQ * INF / 16;             // 1,048,576 per source
    int v = blockIdx.x * 256 + threadIdx.x;
    if (v < 2 * NC16) {
        int isH = v >= NC16;
        int u16 = v - (isH ? NC16 : 0);
        const float4* src = isH ? hp : inp;
        float4 x0 = src[u16 * 4];
        float4 x1 = src[u16 * 4 + 1];
        float4 x2 = src[u16 * 4 + 2];
        float4 x3 = src[u16 * 4 + 3];
        int u = u16 * 16;
        int b = u >> 11;
        int k = u & 2047;
        unsigned short* d = comb + (size_t)b * KK + k + (isH ? INF : 0);
        *(ushort8*)d       = cvt8(x0, x1);
        *(ushort8*)(d + 8) = cvt8(x2, x3);
    } else {
        int w = v - 2 * NC16;
        size_t e = (size_t)w * 16;
        int g = (int)(e >> 23);
        int u = (int)(e & ((1u << 23) - 1));
        int h = u >> 12;
        int k = u & 4095;
        const float4* src = (g == 0) ? w0 : (g == 1) ? w1 : (g == 2) ? w2 : w3;
        float4 x0 = src[(u >> 2)];
        float4 x1 = src[(u >> 2) + 1];
        float4 x2 = src[(u >> 2) + 2];
        float4 x3 = src[(u >> 2) + 3];
        int p = ((h >> 5) << 7) + (g << 5) + (h & 31);
        unsigned short* d = wpk + (size_t)p * KK + k;
        *(ushort8*)d       = cvt8(x0, x1);
        *(ushort8*)(d + 8) = cvt8(x2, x3);
    }
}

// ---- fused 256x256 8-phase GEMM + in-register LSTM epilogue ----
// 512 threads = 8 waves, wave grid 4(M) x 2(N): per-wave 64 rows x 128 cols.
// LDS 128 KiB: [A0 | B0 | A1 | B1] @ 32 KiB each, XOR-swizzled 16B chunks.
// Phases: each phase = {ds reads || 1 STAGE} BAR {16 MFMA} BAR.
// Reads: ph1 = all-A (8) + B-pair0 (4); ph2..4 = one B-pair (4 each).
__global__ __launch_bounds__(512, 2) void lstm_fused(
    const unsigned short* __restrict__ A,   // combined bf16 [8192][4096]
    const unsigned short* __restrict__ W,   // packed bf16 [8192][4096]
    const float* __restrict__ cprev,
    const float* __restrict__ bf_, const float* __restrict__ bi_,
    const float* __restrict__ bg_, const float* __restrict__ bo_,
    float* __restrict__ out)
{
    __shared__ unsigned short lds[65536];   // 128 KiB
    char* ldsb = (char*)lds;

    const int t    = threadIdx.x;
    const int wv   = t >> 6;
    const int lane = t & 63;
    const int wm   = wv >> 1;      // 0..3 -> row base wm*64
    const int wn   = wv & 1;       // 0..1 -> col base wn*128
    const int fr   = lane & 15;
    const int fq   = lane >> 4;

    // bijective XCD swizzle (1024 wgs, 1024%8==0)
    int lin = blockIdx.y * 32 + blockIdx.x;
    lin = (lin & 7) * 128 + (lin >> 3);
    const int m0 = (lin >> 5) << 8;        // batch tile base (256 rows)
    const int n0 = (lin & 31) << 8;        // packed-col tile base (256)

    // staging source: lane covers row (wv*16 + lane>>3), swizzled k-chunk
    const int koff = ((lane & 7) ^ (lane >> 3)) << 3;   // elements
    const unsigned short* aR = A + (size_t)(m0 + wv * 16 + (lane >> 3)) * KK + koff;
    const unsigned short* bR = W + (size_t)(n0 + wv * 16 + (lane >> 3)) * KK + koff;
    const int stgOff = wv * 16 * 128;      // LDS byte offset of wave's 16 rows

    // fragment-read bases (byte offsets into LDS)
    const int x7    = fr & 7;
    const int aBase = (wm >> 1) * 16384 + ((wm & 1) * 64 + fr) * 128;
    const int bBase = 32768 + wn * 16384 + fr * 128;

    floatx4 acc[4][8];
#pragma unroll
    for (int i = 0; i < 4; ++i)
#pragma unroll
        for (int j = 0; j < 8; ++j) acc[i][j] = (floatx4)0.f;

    short8 aA[4][2];   // all 4 A fragments x ks (held through a side)
    short8 bb[2][2];   // one B-pair x ks

#define STAGE(srcbase, ldsoff, kk)                                              \
    do {                                                                        \
        __builtin_amdgcn_global_load_lds(                                       \
            (const __attribute__((address_space(1))) void*)((srcbase) + (kk)),  \
            (__attribute__((address_space(3))) void*)(ldsb + (ldsoff) + stgOff),\
            16, 0, 0);                                                          \
        __builtin_amdgcn_global_load_lds(                                       \
            (const __attribute__((address_space(1))) void*)((srcbase) + 8 * KK + (kk)), \
            (__attribute__((address_space(3))) void*)(ldsb + (ldsoff) + stgOff + 1024), \
            16, 0, 0);                                                          \
    } while (0)

    auto LDA = [&](int side, int i, short8* d) {
        const char* p = ldsb + side * 65536 + aBase + i * 2048;
        d[0] = *(const short8*)(p + ((fq ^ x7) << 4));
        d[1] = *(const short8*)(p + (((4 + fq) ^ x7) << 4));
    };
    auto LDB = [&](int side, int j, short8* d) {
        const char* p = ldsb + side * 65536 + bBase + j * 2048;
        d[0] = *(const short8*)(p + ((fq ^ x7) << 4));
        d[1] = *(const short8*)(p + (((4 + fq) ^ x7) << 4));
    };
    auto MM = [&](const short8* a, const short8* b, floatx4& c) {
        c = __builtin_amdgcn_mfma_f32_16x16x32_bf16(a[0], b[0], c, 0, 0, 0);
        c = __builtin_amdgcn_mfma_f32_16x16x32_bf16(a[1], b[1], c, 0, 0, 0);
    };

#define BAR()  __builtin_amdgcn_s_barrier()
#define SB0()  __builtin_amdgcn_sched_barrier(0)
#define VM4()  do { asm volatile("s_waitcnt vmcnt(4)" ::: "memory"); SB0(); } while (0)

    // MFMA cluster for B-pair p (16 MFMA)
#define CLUSTER(p)                                                    \
    do {                                                              \
        __builtin_amdgcn_s_setprio(1);                                \
        _Pragma("unroll")                                             \
        for (int i = 0; i < 4; ++i) {                                 \
            MM(aA[i], bb[0], acc[i][2 * (p)]);                        \
            MM(aA[i], bb[1], acc[i][2 * (p) + 1]);                    \
        }                                                             \
        __builtin_amdgcn_s_setprio(0);                                \
    } while (0)

    // prologue: A(0),B(0)->s0 ; A(1)->s1
    STAGE(aR, 0, 0);
    STAGE(aR + 128 * KK, 16384, 0);
    STAGE(bR, 32768, 0);
    STAGE(bR + 128 * KK, 49152, 0);
    STAGE(aR, 65536, 64);
    STAGE(aR + 128 * KK, 81920, 64);
    VM4();   // A(0)+B(0) landed; A(1) may be in flight
    BAR();

#pragma unroll 1
    for (int it = 0; it < 32; ++it) {
        const int k1 = ((2 * it + 1) & 63) << 6;
        const int k2 = ((2 * it + 2) & 63) << 6;
        const int k3 = ((2 * it + 3) & 63) << 6;

        // ---- ph1 (side0): all A + B-pair0; stage B-lo(u+1)->s1 ----
        LDA(0, 0, aA[0]); LDB(0, 0, bb[0]); LDB(0, 1, bb[1]);
        LDA(0, 1, aA[1]); LDA(0, 2, aA[2]); LDA(0, 3, aA[3]);
        STAGE(bR, 98304, k1);
        SB0(); BAR();
        CLUSTER(0);
        BAR();

        // ---- ph2: B-pair1; stage B-hi(u+1)->s1 ----
        LDB(0, 2, bb[0]); LDB(0, 3, bb[1]);
        STAGE(bR + 128 * KK, 114688, k1);
        SB0(); BAR();
        CLUSTER(1);
        BAR();

        // ---- ph3: B-pair2; stage A-lo(u+2)->s0 (s0-A reads done @ph1) ----
        LDB(0, 4, bb[0]); LDB(0, 5, bb[1]);
        STAGE(aR, 0, k2);
        SB0(); BAR();
        CLUSTER(2);
        BAR();

        // ---- ph4: B-pair3; stage A-hi(u+2)->s0; counted vmcnt ----
        LDB(0, 6, bb[0]); LDB(0, 7, bb[1]);
        STAGE(aR + 128 * KK, 16384, k2);
        SB0(); BAR();
        CLUSTER(3);
        VM4();   // A(u+1)+B(u+1) landed for ph5; A(u+2) in flight
        BAR();

        // ---- ph5 (side1): all A + B-pair0; stage B-lo(u+2)->s0 ----
        LDA(1, 0, aA[0]); LDB(1, 0, bb[0]); LDB(1, 1, bb[1]);
        LDA(1, 1, aA[1]); LDA(1, 2, aA[2]); LDA(1, 3, aA[3]);
        STAGE(bR, 32768, k2);
        SB0(); BAR();
        CLUSTER(0);
        BAR();

        // ---- ph6: B-pair1; stage B-hi(u+2)->s0 ----
        LDB(1, 2, bb[0]); LDB(1, 3, bb[1]);
        STAGE(bR + 128 * KK, 49152, k2);
        SB0(); BAR();
        CLUSTER(1);
        BAR();

        // ---- ph7: B-pair2; stage A-lo(u+3)->s1 (s1-A reads done @ph5) ----
        LDB(1, 4, bb[0]); LDB(1, 5, bb[1]);
        STAGE(aR, 65536, k3);
        SB0(); BAR();
        CLUSTER(2);
        BAR();

        // ---- ph8: B-pair3; stage A-hi(u+3)->s1; counted vmcnt ----
        LDB(1, 6, bb[0]); LDB(1, 7, bb[1]);
        STAGE(aR + 128 * KK, 81920, k3);
        SB0(); BAR();
        CLUSTER(3);
        VM4();   // A(u+2)+B(u+2) landed for next ph1; A(u+3) in flight
        BAR();
    }

    // ---- in-register LSTM epilogue ----
    // acc[i][j][r]: row = m0 + wm*64 + i*16 + fq*4 + r
    //              packed col = n0 + wn*128 + j*16 + fr
    //              -> gate = j>>1, h = (n0>>2) + wn*32 + (j&1)*16 + fr
    const int hb = (n0 >> 2) + wn * 32;
    float bF[2], bI[2], bG[2], bO[2];
#pragma unroll
    for (int jh = 0; jh < 2; ++jh) {
        int h = hb + jh * 16 + fr;
        bF[jh] = bf_[h]; bI[jh] = bi_[h]; bG[jh] = bg_[h]; bO[jh] = bo_[h];
    }
    const int rowb = m0 + wm * 64 + fq * 4;
#pragma unroll
    for (int i = 0; i < 4; ++i) {
#pragma unroll
        for (int r = 0; r < 4; ++r) {
            int row = rowb + i * 16 + r;
#pragma unroll
            for (int jh = 0; jh < 2; ++jh) {
                int h = hb + jh * 16 + fr;
                size_t gi = (size_t)row * HH + h;
                float xf = acc[i][0 + jh][r] + bF[jh];
                float xi = acc[i][2 + jh][r] + bI[jh];
                float xg = acc[i][4 + jh][r] + bG[jh];
                float xo = acc[i][6 + jh][r] + bO[jh];
                float f  = fsig(xf);
                float ii = fsig(xi);
                float g  = ftanh(xg);
                float o  = fsig(xo);
                float c  = f * cprev[gi] + ii * g;
                float hv = o * ftanh(c);
                out[gi] = hv;
                out[(size_t)BQ * HH + gi] = c;
            }
        }
    }
}

extern "C" void kernel_launch(void* const* d_in, const int* in_sizes, int n_in,
                              void* d_out, int out_size, void* d_ws, size_t ws_size,
                              hipStream_t stream) {
    const float* input  = (const float*)d_in[0];
    const float* h_prev = (const float*)d_in[1];
    const float* c_prev = (const float*)d_in[2];
    const float* Wf = (const float*)d_in[3];
    const float* bf_ = (const float*)d_in[4];
    const float* Wi = (const float*)d_in[5];
    const float* bi_ = (const float*)d_in[6];
    const float* Wg = (const float*)d_in[7];
    const float* bg_ = (const float*)d_in[8];
    const float* Wo = (const float*)d_in[9];
    const float* bo_ = (const float*)d_in[10];
    float* out = (float*)d_out;

    unsigned short* combined = (unsigned short*)d_ws;                   // 64 MB
    unsigned short* Wpk = (unsigned short*)d_ws + (size_t)BQ * KK;      // 64 MB

    pack_all<<<dim3(16384), 256, 0, stream>>>(
        (const float4*)input, (const float4*)h_prev,
        (const float4*)Wf, (const float4*)Wi, (const float4*)Wg, (const float4*)Wo,
        combined, Wpk);
    lstm_fused<<<dim3(32, 32), 512, 0, stream>>>(
        combined, Wpk, c_prev, bf_, bi_, bg_, bo_, out);
}

// Round 4
// 797.146 us; speedup vs baseline: 1.4642x; 1.0118x over previous
//
#include <hip/hip_runtime.h>
#include <stdint.h>

// LSTM cell. B=8192, IN=2048, H=2048.
// R6: single-barrier phases. R5's {reads|STAGE} BAR {MFMA} BAR lockstep idles
// the MFMA pipe during reads and vice versa; hazard audit shows the mid-phase
// barrier is redundant (every buffer's last read is consumed by that phase's
// own MFMA cluster before the end barrier; staged-data validity is per-wave
// vmcnt(4) + the adjacent end barrier at ph4/ph8). New phase:
//   { ds reads ; STAGE ; SB0 ; setprio(1) MFMA setprio(0) ; [VM4] ; BAR }
// -> 8 barriers/iter instead of 16, and waves overlap reads with MFMA.

#define BQ 8192
#define INF 2048
#define HH 2048
#define KK 4096   // IN + H

typedef __attribute__((ext_vector_type(8))) short short8;
typedef __attribute__((ext_vector_type(8))) unsigned short ushort8;
typedef __attribute__((ext_vector_type(4))) float floatx4;

__device__ __forceinline__ unsigned short f2b(float f) {
    unsigned u = __float_as_uint(f);
    u += 0x7fff + ((u >> 16) & 1);   // round-to-nearest-even
    return (unsigned short)(u >> 16);
}
__device__ __forceinline__ ushort8 cvt8(float4 a, float4 b) {
    ushort8 y;
    y[0] = f2b(a.x); y[1] = f2b(a.y); y[2] = f2b(a.z); y[3] = f2b(a.w);
    y[4] = f2b(b.x); y[5] = f2b(b.y); y[6] = f2b(b.z); y[7] = f2b(b.w);
    return y;
}
__device__ __forceinline__ float fsig(float x) {
    return 1.f / (1.f + __expf(-x));
}
__device__ __forceinline__ float ftanh(float x) {
    return 1.f - 2.f / (__expf(2.f * x) + 1.f);
}

// ---- single pack kernel: [input|h_prev] -> combined bf16 [8192][4096],
//      Wf..Wo -> gate-interleaved bf16 W [8192][4096] (p=(h>>5)*128+g*32+(h&31))
__global__ __launch_bounds__(256) void pack_all(
    const float4* __restrict__ inp, const float4* __restrict__ hp,
    const float4* __restrict__ w0, const float4* __restrict__ w1,
    const float4* __restrict__ w2, const float4* __restrict__ w3,
    unsigned short* __restrict__ comb, unsigned short* __restrict__ wpk)
{
    const int NC16 = BQ * INF / 16;             // 1,048,576 per source
    int v = blockIdx.x * 256 + threadIdx.x;
    if (v < 2 * NC16) {
        int isH = v >= NC16;
        int u16 = v - (isH ? NC16 : 0);
        const float4* src = isH ? hp : inp;
        float4 x0 = src[u16 * 4];
        float4 x1 = src[u16 * 4 + 1];
        float4 x2 = src[u16 * 4 + 2];
        float4 x3 = src[u16 * 4 + 3];
        int u = u16 * 16;
        int b = u >> 11;
        int k = u & 2047;
        unsigned short* d = comb + (size_t)b * KK + k + (isH ? INF : 0);
        *(ushort8*)d       = cvt8(x0, x1);
        *(ushort8*)(d + 8) = cvt8(x2, x3);
    } else {
        int w = v - 2 * NC16;
        size_t e = (size_t)w * 16;
        int g = (int)(e >> 23);
        int u = (int)(e & ((1u << 23) - 1));
        int h = u >> 12;
        int k = u & 4095;
        const float4* src = (g == 0) ? w0 : (g == 1) ? w1 : (g == 2) ? w2 : w3;
        float4 x0 = src[(u >> 2)];
        float4 x1 = src[(u >> 2) + 1];
        float4 x2 = src[(u >> 2) + 2];
        float4 x3 = src[(u >> 2) + 3];
        int p = ((h >> 5) << 7) + (g << 5) + (h & 31);
        unsigned short* d = wpk + (size_t)p * KK + k;
        *(ushort8*)d       = cvt8(x0, x1);
        *(ushort8*)(d + 8) = cvt8(x2, x3);
    }
}

// ---- fused 256x256 8-phase GEMM + in-register LSTM epilogue ----
// 512 threads = 8 waves, wave grid 4(M) x 2(N): per-wave 64 rows x 128 cols.
// LDS 128 KiB: [A0 | B0 | A1 | B1] @ 32 KiB each, XOR-swizzled 16B chunks.
// Reads: ph1 = all-A (8) + B-pair0 (4); ph2..4 = one B-pair (4 each).
// ONE barrier per phase (end); counted vmcnt(4) at ph4/ph8 only.
__global__ __launch_bounds__(512, 2) void lstm_fused(
    const unsigned short* __restrict__ A,   // combined bf16 [8192][4096]
    const unsigned short* __restrict__ W,   // packed bf16 [8192][4096]
    const float* __restrict__ cprev,
    const float* __restrict__ bf_, const float* __restrict__ bi_,
    const float* __restrict__ bg_, const float* __restrict__ bo_,
    float* __restrict__ out)
{
    __shared__ unsigned short lds[65536];   // 128 KiB
    char* ldsb = (char*)lds;

    const int t    = threadIdx.x;
    const int wv   = t >> 6;
    const int lane = t & 63;
    const int wm   = wv >> 1;      // 0..3 -> row base wm*64
    const int wn   = wv & 1;       // 0..1 -> col base wn*128
    const int fr   = lane & 15;
    const int fq   = lane >> 4;

    // bijective XCD swizzle (1024 wgs, 1024%8==0)
    int lin = blockIdx.y * 32 + blockIdx.x;
    lin = (lin & 7) * 128 + (lin >> 3);
    const int m0 = (lin >> 5) << 8;        // batch tile base (256 rows)
    const int n0 = (lin & 31) << 8;        // packed-col tile base (256)

    // staging source: lane covers row (wv*16 + lane>>3), swizzled k-chunk
    const int koff = ((lane & 7) ^ (lane >> 3)) << 3;   // elements
    const unsigned short* aR = A + (size_t)(m0 + wv * 16 + (lane >> 3)) * KK + koff;
    const unsigned short* bR = W + (size_t)(n0 + wv * 16 + (lane >> 3)) * KK + koff;
    const int stgOff = wv * 16 * 128;      // LDS byte offset of wave's 16 rows

    // fragment-read bases (byte offsets into LDS)
    const int x7    = fr & 7;
    const int aBase = (wm >> 1) * 16384 + ((wm & 1) * 64 + fr) * 128;
    const int bBase = 32768 + wn * 16384 + fr * 128;

    floatx4 acc[4][8];
#pragma unroll
    for (int i = 0; i < 4; ++i)
#pragma unroll
        for (int j = 0; j < 8; ++j) acc[i][j] = (floatx4)0.f;

    short8 aA[4][2];   // all 4 A fragments x ks (held through a side)
    short8 bb[2][2];   // one B-pair x ks

#define STAGE(srcbase, ldsoff, kk)                                              \
    do {                                                                        \
        __builtin_amdgcn_global_load_lds(                                       \
            (const __attribute__((address_space(1))) void*)((srcbase) + (kk)),  \
            (__attribute__((address_space(3))) void*)(ldsb + (ldsoff) + stgOff),\
            16, 0, 0);                                                          \
        __builtin_amdgcn_global_load_lds(                                       \
            (const __attribute__((address_space(1))) void*)((srcbase) + 8 * KK + (kk)), \
            (__attribute__((address_space(3))) void*)(ldsb + (ldsoff) + stgOff + 1024), \
            16, 0, 0);                                                          \
    } while (0)

    auto LDA = [&](int side, int i, short8* d) {
        const char* p = ldsb + side * 65536 + aBase + i * 2048;
        d[0] = *(const short8*)(p + ((fq ^ x7) << 4));
        d[1] = *(const short8*)(p + (((4 + fq) ^ x7) << 4));
    };
    auto LDB = [&](int side, int j, short8* d) {
        const char* p = ldsb + side * 65536 + bBase + j * 2048;
        d[0] = *(const short8*)(p + ((fq ^ x7) << 4));
        d[1] = *(const short8*)(p + (((4 + fq) ^ x7) << 4));
    };
    auto MM = [&](const short8* a, const short8* b, floatx4& c) {
        c = __builtin_amdgcn_mfma_f32_16x16x32_bf16(a[0], b[0], c, 0, 0, 0);
        c = __builtin_amdgcn_mfma_f32_16x16x32_bf16(a[1], b[1], c, 0, 0, 0);
    };

#define BAR()  __builtin_amdgcn_s_barrier()
#define SB0()  __builtin_amdgcn_sched_barrier(0)
#define VM4()  do { asm volatile("s_waitcnt vmcnt(4)" ::: "memory"); SB0(); } while (0)

    // MFMA cluster for B-pair p (16 MFMA)
#define CLUSTER(p)                                                    \
    do {                                                              \
        __builtin_amdgcn_s_setprio(1);                                \
        _Pragma("unroll")                                             \
        for (int i = 0; i < 4; ++i) {                                 \
            MM(aA[i], bb[0], acc[i][2 * (p)]);                        \
            MM(aA[i], bb[1], acc[i][2 * (p) + 1]);                    \
        }                                                             \
        __builtin_amdgcn_s_setprio(0);                                \
    } while (0)

    // prologue: A(0),B(0)->s0 ; A(1)->s1
    STAGE(aR, 0, 0);
    STAGE(aR + 128 * KK, 16384, 0);
    STAGE(bR, 32768, 0);
    STAGE(bR + 128 * KK, 49152, 0);
    STAGE(aR, 65536, 64);
    STAGE(aR + 128 * KK, 81920, 64);
    VM4();   // A(0)+B(0) landed; A(1) may be in flight
    BAR();

#pragma unroll 1
    for (int it = 0; it < 32; ++it) {
        const int k1 = ((2 * it + 1) & 63) << 6;
        const int k2 = ((2 * it + 2) & 63) << 6;
        const int k3 = ((2 * it + 3) & 63) << 6;

        // ---- ph1 (side0): all A + B-pair0; stage B-lo(u+1)->s1 ----
        LDA(0, 0, aA[0]); LDB(0, 0, bb[0]); LDB(0, 1, bb[1]);
        LDA(0, 1, aA[1]); LDA(0, 2, aA[2]); LDA(0, 3, aA[3]);
        STAGE(bR, 98304, k1);
        SB0();
        CLUSTER(0);
        BAR();

        // ---- ph2: B-pair1; stage B-hi(u+1)->s1 ----
        LDB(0, 2, bb[0]); LDB(0, 3, bb[1]);
        STAGE(bR + 128 * KK, 114688, k1);
        SB0();
        CLUSTER(1);
        BAR();

        // ---- ph3: B-pair2; stage A-lo(u+2)->s0 (s0-A reads done @ph1) ----
        LDB(0, 4, bb[0]); LDB(0, 5, bb[1]);
        STAGE(aR, 0, k2);
        SB0();
        CLUSTER(2);
        BAR();

        // ---- ph4: B-pair3; stage A-hi(u+2)->s0; counted vmcnt ----
        LDB(0, 6, bb[0]); LDB(0, 7, bb[1]);
        STAGE(aR + 128 * KK, 16384, k2);
        SB0();
        CLUSTER(3);
        VM4();   // B(u+1) + all older landed before ph5; A(u+2) in flight
        BAR();

        // ---- ph5 (side1): all A + B-pair0; stage B-lo(u+2)->s0 ----
        LDA(1, 0, aA[0]); LDB(1, 0, bb[0]); LDB(1, 1, bb[1]);
        LDA(1, 1, aA[1]); LDA(1, 2, aA[2]); LDA(1, 3, aA[3]);
        STAGE(bR, 32768, k2);
        SB0();
        CLUSTER(0);
        BAR();

        // ---- ph6: B-pair1; stage B-hi(u+2)->s0 ----
        LDB(1, 2, bb[0]); LDB(1, 3, bb[1]);
        STAGE(bR + 128 * KK, 49152, k2);
        SB0();
        CLUSTER(1);
        BAR();

        // ---- ph7: B-pair2; stage A-lo(u+3)->s1 (s1-A reads done @ph5) ----
        LDB(1, 4, bb[0]); LDB(1, 5, bb[1]);
        STAGE(aR, 65536, k3);
        SB0();
        CLUSTER(2);
        BAR();

        // ---- ph8: B-pair3; stage A-hi(u+3)->s1; counted vmcnt ----
        LDB(1, 6, bb[0]); LDB(1, 7, bb[1]);
        STAGE(aR + 128 * KK, 81920, k3);
        SB0();
        CLUSTER(3);
        VM4();   // A(u+2)+B(u+2) landed before next ph1; A(u+3) in flight
        BAR();
    }

    // ---- in-register LSTM epilogue ----
    // acc[i][j][r]: row = m0 + wm*64 + i*16 + fq*4 + r
    //              packed col = n0 + wn*128 + j*16 + fr
    //              -> gate = j>>1, h = (n0>>2) + wn*32 + (j&1)*16 + fr
    const int hb = (n0 >> 2) + wn * 32;
    float bF[2], bI[2], bG[2], bO[2];
#pragma unroll
    for (int jh = 0; jh < 2; ++jh) {
        int h = hb + jh * 16 + fr;
        bF[jh] = bf_[h]; bI[jh] = bi_[h]; bG[jh] = bg_[h]; bO[jh] = bo_[h];
    }
    const int rowb = m0 + wm * 64 + fq * 4;
#pragma unroll
    for (int i = 0; i < 4; ++i) {
#pragma unroll
        for (int r = 0; r < 4; ++r) {
            int row = rowb + i * 16 + r;
#pragma unroll
            for (int jh = 0; jh < 2; ++jh) {
                int h = hb + jh * 16 + fr;
                size_t gi = (size_t)row * HH + h;
                float xf = acc[i][0 + jh][r] + bF[jh];
                float xi = acc[i][2 + jh][r] + bI[jh];
                float xg = acc[i][4 + jh][r] + bG[jh];
                float xo = acc[i][6 + jh][r] + bO[jh];
                float f  = fsig(xf);
                float ii = fsig(xi);
                float g  = ftanh(xg);
                float o  = fsig(xo);
                float c  = f * cprev[gi] + ii * g;
                float hv = o * ftanh(c);
                out[gi] = hv;
                out[(size_t)BQ * HH + gi] = c;
            }
        }
    }
}

extern "C" void kernel_launch(void* const* d_in, const int* in_sizes, int n_in,
                              void* d_out, int out_size, void* d_ws, size_t ws_size,
                              hipStream_t stream) {
    const float* input  = (const float*)d_in[0];
    const float* h_prev = (const float*)d_in[1];
    const float* c_prev = (const float*)d_in[2];
    const float* Wf = (const float*)d_in[3];
    const float* bf_ = (const float*)d_in[4];
    const float* Wi = (const float*)d_in[5];
    const float* bi_ = (const float*)d_in[6];
    const float* Wg = (const float*)d_in[7];
    const float* bg_ = (const float*)d_in[8];
    const float* Wo = (const float*)d_in[9];
    const float* bo_ = (const float*)d_in[10];
    float* out = (float*)d_out;

    unsigned short* combined = (unsigned short*)d_ws;                   // 64 MB
    unsigned short* Wpk = (unsigned short*)d_ws + (size_t)BQ * KK;      // 64 MB

    pack_all<<<dim3(16384), 256, 0, stream>>>(
        (const float4*)input, (const float4*)h_prev,
        (const float4*)Wf, (const float4*)Wi, (const float4*)Wg, (const float4*)Wo,
        combined, Wpk);
    lstm_fused<<<dim3(32, 32), 512, 0, stream>>>(
        combined, Wpk, c_prev, bf_, bi_, bg_, bo_, out);
}